// Round 3
// baseline (507.270 us; speedup 1.0000x reference)
//
#include <hip/hip_runtime.h>

typedef __bf16 bf16;
typedef bf16 bf16x4 __attribute__((ext_vector_type(4)));
typedef bf16 bf16x8 __attribute__((ext_vector_type(8)));
typedef float f32x4 __attribute__((ext_vector_type(4)));

#define B_ 2
#define S_ 4096
#define D_ 1024

__device__ __forceinline__ void gload_lds16(const void* g, void* l) {
  __builtin_amdgcn_global_load_lds((const __attribute__((address_space(1))) void*)g,
                                   (__attribute__((address_space(3))) void*)l, 16, 0, 0);
}

// ---------------- convert: f32 -> bf16 elementwise ----------------
__global__ __launch_bounds__(256) void convert_kernel(const float* __restrict__ in,
                                                      bf16* __restrict__ out, int n4) {
  // n4 = n/4
  for (int i = blockIdx.x * 256 + threadIdx.x; i < n4; i += gridDim.x * 256) {
    const float4 v = ((const float4*)in)[i];
    bf16x4 o = {(bf16)v.x, (bf16)v.y, (bf16)v.z, (bf16)v.w};
    *(bf16x4*)&out[i * 4] = o;  // 8 bytes
  }
}

// ---------------- transpose+convert: in f32 [K][N] -> out bf16 [N][K] ----------------
__global__ void transpose_convert(const float* __restrict__ in, bf16* __restrict__ out,
                                  int K, int N) {
  __shared__ float tile[32][33];
  const int nb = blockIdx.x * 32;
  const int kb = blockIdx.y * 32;
  const int tx = threadIdx.x, ty = threadIdx.y;
#pragma unroll
  for (int j = 0; j < 4; j++)
    tile[ty + j * 8][tx] = in[(size_t)(kb + ty + j * 8) * N + nb + tx];
  __syncthreads();
#pragma unroll
  for (int j = 0; j < 4; j++)
    out[(size_t)(nb + ty + j * 8) * K + kb + tx] = (bf16)tile[tx][ty + j * 8];
}

// ---------------- GEMM: C[M][N] = A[M][K] * Bt[N][K]^T + bias[N] ----------------
template <typename OutT>
__global__ __launch_bounds__(256) void gemm_bias_kernel(
    const bf16* __restrict__ A, const bf16* __restrict__ Bt,
    const float* __restrict__ bias, OutT* __restrict__ C,
    int M, int N, int K)
{
  __shared__ __align__(16) bf16 Al[128 * 32];
  __shared__ __align__(16) bf16 Bl[128 * 32];
  const int m0 = blockIdx.x * 128;
  const int n0 = blockIdx.y * 128;
  const int t = threadIdx.x;
  const int lane = t & 63;
  const int wave = t >> 6;
  const int wr = (wave >> 1) * 64;
  const int wc = (wave & 1) * 64;
  const int r16 = lane & 15;
  const int kg = lane >> 4;

  f32x4 acc[4][4];
#pragma unroll
  for (int i = 0; i < 4; i++)
#pragma unroll
    for (int j = 0; j < 4; j++) {
      f32x4 z = {0.f, 0.f, 0.f, 0.f};
      acc[i][j] = z;
    }

  for (int k0 = 0; k0 < K; k0 += 32) {
    __syncthreads();
#pragma unroll
    for (int i = 0; i < 2; i++) {
      const int o = i * 4096 + wave * 1024 + lane * 16;  // byte offset in 8KB tile
      const int r = o >> 6;     // row (64B = 32 bf16 per row)
      const int cb = o & 63;    // byte within row
      gload_lds16((const char*)(A + (size_t)(m0 + r) * K + k0) + cb,
                  (char*)Al + i * 4096 + wave * 1024);
      gload_lds16((const char*)(Bt + (size_t)(n0 + r) * K + k0) + cb,
                  (char*)Bl + i * 4096 + wave * 1024);
    }
    __syncthreads();
    bf16x8 a[4], b[4];
#pragma unroll
    for (int i = 0; i < 4; i++)
      a[i] = *(const bf16x8*)&Al[(wr + i * 16 + r16) * 32 + kg * 8];
#pragma unroll
    for (int i = 0; i < 4; i++)
      b[i] = *(const bf16x8*)&Bl[(wc + i * 16 + r16) * 32 + kg * 8];
#pragma unroll
    for (int i = 0; i < 4; i++)
#pragma unroll
      for (int j = 0; j < 4; j++)
        acc[i][j] = __builtin_amdgcn_mfma_f32_16x16x32_bf16(a[i], b[j], acc[i][j], 0, 0, 0);
  }

  float bs[4];
#pragma unroll
  for (int j = 0; j < 4; j++) bs[j] = bias[n0 + wc + j * 16 + r16];
#pragma unroll
  for (int i = 0; i < 4; i++)
#pragma unroll
    for (int j = 0; j < 4; j++)
#pragma unroll
      for (int r = 0; r < 4; r++) {
        const int row = m0 + wr + i * 16 + kg * 4 + r;
        const int col = n0 + wc + j * 16 + r16;
        C[(size_t)row * N + col] = (OutT)(acc[i][j][r] + bs[j]);
      }
}

// ---------------- pooling: pooled[b][l][d] = mean_{c<64} x[b][l*64+c][d] ----------------
__global__ __launch_bounds__(256) void pool_kernel(const float* __restrict__ x,
                                                   bf16* __restrict__ pooled) {
  const int blk = blockIdx.x;           // b*64 + l
  const int b = blk >> 6, lt = blk & 63;
  const int t = threadIdx.x;
  for (int d = t; d < D_; d += 256) {
    const float* p = x + ((size_t)b * S_ + lt * 64) * D_ + d;
    float sum = 0.f;
#pragma unroll
    for (int c = 0; c < 64; c++) sum += p[(size_t)c * D_];
    pooled[(size_t)blk * D_ + d] = (bf16)(sum * 0.015625f);
  }
}

// ---------------- latent attention ----------------
// rqb:(B,S,256)  rkvb:(B*64,512) [rk cols 0..255, rv cols 256..511] -> latout:(B,S,256)
__global__ __launch_bounds__(256) void latent_attn_kernel(
    const bf16* __restrict__ rqb, const bf16* __restrict__ rkvb,
    bf16* __restrict__ latout)
{
  __shared__ float rq_s[256];
  __shared__ float attn_s[4][64];
  const int blk = blockIdx.x;
  const int b = blk >> 12, s = blk & 4095;
  const int t = threadIdx.x;
  const int h = t >> 6, l = t & 63;
  const int cid = s >> 6;
  rq_s[t] = (float)rqb[((size_t)b * S_ + s) * 256 + t];
  __syncthreads();
  float val = -1e30f;
  if (l < cid) {
    const bf16* kr = rkvb + (size_t)(b * 64 + l) * 512 + h * 64;
    float sum = 0.f;
#pragma unroll
    for (int c = 0; c < 8; c++) {
      bf16x8 kv = *(const bf16x8*)(kr + c * 8);
#pragma unroll
      for (int j = 0; j < 8; j++) sum += rq_s[h * 64 + c * 8 + j] * (float)kv[j];
    }
    val = sum * 0.125f;
  }
  float mx = val;
#pragma unroll
  for (int off = 32; off; off >>= 1) mx = fmaxf(mx, __shfl_xor(mx, off));
  const float p = (l < cid) ? __expf(val - mx) : 0.f;
  float sm = p;
#pragma unroll
  for (int off = 32; off; off >>= 1) sm += __shfl_xor(sm, off);
  attn_s[h][l] = (sm > 0.f) ? p / sm : 0.f;
  __syncthreads();
  float o = 0.f;
  const bf16* vb = rkvb + (size_t)b * 64 * 512 + 256 + h * 64 + l;
  for (int lat = 0; lat < cid; lat++) o += attn_s[h][lat] * (float)vb[(size_t)lat * 512];
  latout[((size_t)b * S_ + s) * 256 + h * 64 + l] = (bf16)o;
}

// ---------------- local windowed attention (window=128, strictly causal) ----------------
// qkv:(B,S,3072) q cols 0..1023, k cols 1024..2047, v cols 2048..3071 (head h = 64-col slice)
__global__ __launch_bounds__(128) void local_attn_kernel(
    const bf16* __restrict__ qkv, bf16* __restrict__ localb)
{
  __shared__ __align__(16) bf16 Kl[128 * 72];
  __shared__ __align__(16) bf16 Vl[128 * 72];
  const int q0 = blockIdx.x * 128;
  const int h = blockIdx.y;
  const int b = blockIdx.z;
  const int t = threadIdx.x;
  const bf16* kbase = qkv + (size_t)b * S_ * 3072 + 1024 + h * 64;
  const bf16* vbase = kbase + 1024;
  const int q = q0 + t;

  float qf[64];
  {
    const bf16* qptr = qkv + ((size_t)b * S_ + q) * 3072 + h * 64;
#pragma unroll
    for (int c = 0; c < 8; c++) {
      bf16x8 v = *(const bf16x8*)(qptr + c * 8);
#pragma unroll
      for (int j = 0; j < 8; j++) qf[c * 8 + j] = (float)v[j] * 0.125f;
    }
  }
  float of[64];
#pragma unroll
  for (int d = 0; d < 64; d++) of[d] = 0.f;
  float m = -1e30f, lsum = 0.f;
  const int lo = q >= 128 ? q - 128 : 0;

  for (int tt = 0; tt < 2; tt++) {
    const int base = q0 - 128 + tt * 128;
    __syncthreads();
#pragma unroll
    for (int i = 0; i < 8; i++) {
      const int chunk = i * 128 + t;
      const int r = chunk >> 3, c = chunk & 7;
      const int kgl = base + r;
      if (kgl >= 0) {
        *(bf16x8*)&Kl[r * 72 + c * 8] = *(const bf16x8*)(kbase + (size_t)kgl * 3072 + c * 8);
        *(bf16x8*)&Vl[r * 72 + c * 8] = *(const bf16x8*)(vbase + (size_t)kgl * 3072 + c * 8);
      }
    }
    __syncthreads();
    const int kstart = lo > base ? lo : base;
    const int kend = (q < base + 128) ? q : (base + 128);
    for (int k = kstart; k < kend; k++) {
      const int r = k - base;
      float s = 0.f;
#pragma unroll
      for (int c = 0; c < 8; c++) {
        bf16x8 kv = *(const bf16x8*)&Kl[r * 72 + c * 8];
#pragma unroll
        for (int j = 0; j < 8; j++) s += qf[c * 8 + j] * (float)kv[j];
      }
      const float mn = fmaxf(m, s);
      const float corr = __expf(m - mn);
      const float p = __expf(s - mn);
      m = mn;
      lsum = lsum * corr + p;
#pragma unroll
      for (int c = 0; c < 8; c++) {
        bf16x8 vv = *(const bf16x8*)&Vl[r * 72 + c * 8];
#pragma unroll
        for (int j = 0; j < 8; j++) of[c * 8 + j] = of[c * 8 + j] * corr + p * (float)vv[j];
      }
    }
  }

  bf16* outp = localb + ((size_t)b * S_ + q) * 1024 + h * 64;
  const float inv = lsum > 0.f ? 1.f / lsum : 0.f;
#pragma unroll
  for (int d = 0; d < 64; d++) outp[d] = (bf16)(of[d] * inv);
}

// ---------------- gate + mix ----------------
__global__ __launch_bounds__(1024) void gate_mix_kernel(
    const bf16* __restrict__ localb, const bf16* __restrict__ remote,
    const float* __restrict__ glw, const float* __restrict__ grw,
    bf16* __restrict__ mixed)
{
  const int blk = blockIdx.x;
  const int b = blk >> 12, s = blk & 4095;
  const int t = threadIdx.x;
  const int d = t & 63;
  const size_t idx = ((size_t)b * S_ + s) * 1024 + t;
  const float lf = (float)localb[idx], rf = (float)remote[idx];
  float part = lf * glw[d] + rf * grw[d];
#pragma unroll
  for (int off = 32; off; off >>= 1) part += __shfl_xor(part, off);
  const float g = 1.f / (1.f + __expf(-part));
  mixed[idx] = (bf16)(g * lf + (1.f - g) * rf);
}

// ---------------- launch ----------------
extern "C" void kernel_launch(void* const* d_in, const int* in_sizes, int n_in,
                              void* d_out, int out_size, void* d_ws, size_t ws_size,
                              hipStream_t stream)
{
  const float* x      = (const float*)d_in[0];
  const float* qkv_w  = (const float*)d_in[1];
  const float* qkv_b  = (const float*)d_in[2];
  const float* rq_w   = (const float*)d_in[3];
  const float* rq_b   = (const float*)d_in[4];
  const float* rkv_w  = (const float*)d_in[5];
  const float* rkv_b  = (const float*)d_in[6];
  const float* rout_w = (const float*)d_in[7];
  const float* rout_b = (const float*)d_in[8];
  const float* out_w  = (const float*)d_in[9];
  const float* out_b  = (const float*)d_in[10];
  const float* gl_w   = (const float*)d_in[11];
  const float* gr_w   = (const float*)d_in[12];

  char* w = (char*)d_ws;
  bf16* qkv_wt = (bf16*)w; w += (size_t)3072 * 1024 * 2;
  bf16* rq_wt  = (bf16*)w; w += (size_t)256 * 1024 * 2;
  bf16* rkv_wt = (bf16*)w; w += (size_t)512 * 1024 * 2;
  bf16* rout_wt= (bf16*)w; w += (size_t)1024 * 256 * 2;
  bf16* out_wt = (bf16*)w; w += (size_t)1024 * 1024 * 2;
  bf16* xb     = (bf16*)w; w += (size_t)B_ * S_ * 1024 * 2;
  bf16* qkvb   = (bf16*)w; w += (size_t)B_ * S_ * 3072 * 2;
  bf16* pooled = (bf16*)w; w += (size_t)B_ * 64 * 1024 * 2;
  bf16* rqb    = (bf16*)w; w += (size_t)B_ * S_ * 256 * 2;
  bf16* rkvb   = (bf16*)w; w += (size_t)B_ * 64 * 512 * 2;
  bf16* latout = (bf16*)w; w += (size_t)B_ * S_ * 256 * 2;
  bf16* remote = (bf16*)w; w += (size_t)B_ * S_ * 1024 * 2;
  bf16* localb = (bf16*)w; w += (size_t)B_ * S_ * 1024 * 2;
  bf16* mixed  = qkvb;  // reuse: qkvb dead after local_attn

  const dim3 tb(32, 8);
  transpose_convert<<<dim3(96, 32), tb, 0, stream>>>(qkv_w, qkv_wt, 1024, 3072);
  transpose_convert<<<dim3(8, 32),  tb, 0, stream>>>(rq_w, rq_wt, 1024, 256);
  transpose_convert<<<dim3(16, 32), tb, 0, stream>>>(rkv_w, rkv_wt, 1024, 512);
  transpose_convert<<<dim3(32, 8),  tb, 0, stream>>>(rout_w, rout_wt, 256, 1024);
  transpose_convert<<<dim3(32, 32), tb, 0, stream>>>(out_w, out_wt, 1024, 1024);
  convert_kernel<<<dim3(2048), 256, 0, stream>>>(x, xb, B_ * S_ * 1024 / 4);

  gemm_bias_kernel<bf16><<<dim3(64, 24), 256, 0, stream>>>(xb, qkv_wt, qkv_b, qkvb, B_ * S_, 3072, 1024);
  pool_kernel<<<dim3(B_ * 64), 256, 0, stream>>>(x, pooled);
  gemm_bias_kernel<bf16><<<dim3(64, 2), 256, 0, stream>>>(xb, rq_wt, rq_b, rqb, B_ * S_, 256, 1024);
  gemm_bias_kernel<bf16><<<dim3(1, 4), 256, 0, stream>>>(pooled, rkv_wt, rkv_b, rkvb, B_ * 64, 512, 1024);
  latent_attn_kernel<<<dim3(B_ * S_), 256, 0, stream>>>(rqb, rkvb, latout);
  gemm_bias_kernel<bf16><<<dim3(64, 8), 256, 0, stream>>>(latout, rout_wt, rout_b, remote, B_ * S_, 1024, 256);
  local_attn_kernel<<<dim3(S_ / 128, 16, B_), 128, 0, stream>>>(qkvb, localb);
  gate_mix_kernel<<<dim3(B_ * S_), 1024, 0, stream>>>(localb, remote, gl_w, gr_w, mixed);
  gemm_bias_kernel<float><<<dim3(64, 8), 256, 0, stream>>>(mixed, out_wt, out_b, (float*)d_out, B_ * S_, 1024, 1024);
}

// Round 4
// 314.503 us; speedup vs baseline: 1.6129x; 1.6129x over previous
//
#include <hip/hip_runtime.h>

typedef __bf16 bf16;
typedef bf16 bf16x4 __attribute__((ext_vector_type(4)));
typedef bf16 bf16x8 __attribute__((ext_vector_type(8)));
typedef float f32x4 __attribute__((ext_vector_type(4)));

#define B_ 2
#define S_ 4096
#define D_ 1024

__device__ __forceinline__ void gload_lds16(const void* g, void* l) {
  __builtin_amdgcn_global_load_lds((const __attribute__((address_space(1))) void*)g,
                                   (__attribute__((address_space(3))) void*)l, 16, 0, 0);
}

// ---------------- convert: f32 -> bf16 elementwise ----------------
__global__ __launch_bounds__(256) void convert_kernel(const float* __restrict__ in,
                                                      bf16* __restrict__ out, int n4) {
  for (int i = blockIdx.x * 256 + threadIdx.x; i < n4; i += gridDim.x * 256) {
    const float4 v = ((const float4*)in)[i];
    bf16x4 o = {(bf16)v.x, (bf16)v.y, (bf16)v.z, (bf16)v.w};
    *(bf16x4*)&out[i * 4] = o;  // 8 bytes
  }
}

// ---------------- transpose+convert: in f32 [K][N] -> out bf16 [N][K] ----------------
__global__ void transpose_convert(const float* __restrict__ in, bf16* __restrict__ out,
                                  int K, int N) {
  __shared__ float tile[32][33];
  const int nb = blockIdx.x * 32;
  const int kb = blockIdx.y * 32;
  const int tx = threadIdx.x, ty = threadIdx.y;
#pragma unroll
  for (int j = 0; j < 4; j++)
    tile[ty + j * 8][tx] = in[(size_t)(kb + ty + j * 8) * N + nb + tx];
  __syncthreads();
#pragma unroll
  for (int j = 0; j < 4; j++)
    out[(size_t)(nb + ty + j * 8) * K + kb + tx] = (bf16)tile[tx][ty + j * 8];
}

// ---------------- GEMM: C[M][N] = A[M][K] * Bt[N][K]^T + bias[N] ----------------
template <typename OutT>
__global__ __launch_bounds__(256) void gemm_bias_kernel(
    const bf16* __restrict__ A, const bf16* __restrict__ Bt,
    const float* __restrict__ bias, OutT* __restrict__ C,
    int M, int N, int K)
{
  __shared__ __align__(16) bf16 Al[128 * 32];
  __shared__ __align__(16) bf16 Bl[128 * 32];
  const int m0 = blockIdx.x * 128;
  const int n0 = blockIdx.y * 128;
  const int t = threadIdx.x;
  const int lane = t & 63;
  const int wave = t >> 6;
  const int wr = (wave >> 1) * 64;
  const int wc = (wave & 1) * 64;
  const int r16 = lane & 15;
  const int kg = lane >> 4;

  f32x4 acc[4][4];
#pragma unroll
  for (int i = 0; i < 4; i++)
#pragma unroll
    for (int j = 0; j < 4; j++) {
      f32x4 z = {0.f, 0.f, 0.f, 0.f};
      acc[i][j] = z;
    }

  for (int k0 = 0; k0 < K; k0 += 32) {
    __syncthreads();
#pragma unroll
    for (int i = 0; i < 2; i++) {
      const int o = i * 4096 + wave * 1024 + lane * 16;
      const int r = o >> 6;
      const int cb = o & 63;
      gload_lds16((const char*)(A + (size_t)(m0 + r) * K + k0) + cb,
                  (char*)Al + i * 4096 + wave * 1024);
      gload_lds16((const char*)(Bt + (size_t)(n0 + r) * K + k0) + cb,
                  (char*)Bl + i * 4096 + wave * 1024);
    }
    __syncthreads();
    bf16x8 a[4], b[4];
#pragma unroll
    for (int i = 0; i < 4; i++)
      a[i] = *(const bf16x8*)&Al[(wr + i * 16 + r16) * 32 + kg * 8];
#pragma unroll
    for (int i = 0; i < 4; i++)
      b[i] = *(const bf16x8*)&Bl[(wc + i * 16 + r16) * 32 + kg * 8];
#pragma unroll
    for (int i = 0; i < 4; i++)
#pragma unroll
      for (int j = 0; j < 4; j++)
        acc[i][j] = __builtin_amdgcn_mfma_f32_16x16x32_bf16(a[i], b[j], acc[i][j], 0, 0, 0);
  }

  float bs[4];
#pragma unroll
  for (int j = 0; j < 4; j++) bs[j] = bias[n0 + wc + j * 16 + r16];
#pragma unroll
  for (int i = 0; i < 4; i++)
#pragma unroll
    for (int j = 0; j < 4; j++)
#pragma unroll
      for (int r = 0; r < 4; r++) {
        const int row = m0 + wr + i * 16 + kg * 4 + r;
        const int col = n0 + wc + j * 16 + r16;
        C[(size_t)row * N + col] = (OutT)(acc[i][j][r] + bs[j]);
      }
}

// ---------------- pooling ----------------
__global__ __launch_bounds__(256) void pool_kernel(const float* __restrict__ x,
                                                   bf16* __restrict__ pooled) {
  const int blk = blockIdx.x;
  const int b = blk >> 6, lt = blk & 63;
  const int t = threadIdx.x;
  for (int d = t; d < D_; d += 256) {
    const float* p = x + ((size_t)b * S_ + lt * 64) * D_ + d;
    float sum = 0.f;
#pragma unroll
    for (int c = 0; c < 64; c++) sum += p[(size_t)c * D_];
    pooled[(size_t)blk * D_ + d] = (bf16)(sum * 0.015625f);
  }
}

// ---------------- latent attention ----------------
__global__ __launch_bounds__(256) void latent_attn_kernel(
    const bf16* __restrict__ rqb, const bf16* __restrict__ rkvb,
    bf16* __restrict__ latout)
{
  __shared__ float rq_s[256];
  __shared__ float attn_s[4][64];
  const int blk = blockIdx.x;
  const int b = blk >> 12, s = blk & 4095;
  const int t = threadIdx.x;
  const int h = t >> 6, l = t & 63;
  const int cid = s >> 6;
  rq_s[t] = (float)rqb[((size_t)b * S_ + s) * 256 + t];
  __syncthreads();
  float val = -1e30f;
  if (l < cid) {
    const bf16* kr = rkvb + (size_t)(b * 64 + l) * 512 + h * 64;
    float sum = 0.f;
#pragma unroll
    for (int c = 0; c < 8; c++) {
      bf16x8 kv = *(const bf16x8*)(kr + c * 8);
#pragma unroll
      for (int j = 0; j < 8; j++) sum += rq_s[h * 64 + c * 8 + j] * (float)kv[j];
    }
    val = sum * 0.125f;
  }
  float mx = val;
#pragma unroll
  for (int off = 32; off; off >>= 1) mx = fmaxf(mx, __shfl_xor(mx, off));
  const float p = (l < cid) ? __expf(val - mx) : 0.f;
  float sm = p;
#pragma unroll
  for (int off = 32; off; off >>= 1) sm += __shfl_xor(sm, off);
  attn_s[h][l] = (sm > 0.f) ? p / sm : 0.f;
  __syncthreads();
  float o = 0.f;
  const bf16* vb = rkvb + (size_t)b * 64 * 512 + 256 + h * 64 + l;
  for (int lat = 0; lat < cid; lat++) o += attn_s[h][lat] * (float)vb[(size_t)lat * 512];
  latout[((size_t)b * S_ + s) * 256 + h * 64 + l] = (bf16)o;
}

// ---------------- local windowed attention, MFMA version ----------------
// Block = (b, h, 128 q-rows). 4 waves x 32 q-rows. Keys [q0-128, q0+127] in two
// 128-key tiles. K in LDS [128][72] (pad); V transposed [64][136]; P round-trip
// through per-wave LDS [16][136]. mfma_f32_16x16x32_bf16 throughout.
__global__ __launch_bounds__(256) void local_attn_mfma(
    const bf16* __restrict__ qkv, bf16* __restrict__ localb)
{
  __shared__ __align__(16) bf16 Kl[128 * 72];
  __shared__ __align__(16) bf16 Vt[64 * 136];
  __shared__ __align__(16) bf16 Pl[4][16 * 136];

  const int q0 = blockIdx.x * 128;
  const int h  = blockIdx.y;
  const int b  = blockIdx.z;
  const int t  = threadIdx.x;
  const int w  = t >> 6;      // wave 0..3  -> q rows [32w, 32w+32)
  const int l  = t & 63;
  const int g  = l >> 4;      // 0..3
  const int l15 = l & 15;

  const bf16* qbase = qkv + (size_t)b * S_ * 3072 + h * 64;
  const bf16* kbase = qbase + 1024;
  const bf16* vbase = qbase + 2048;

  // Q A-fragments: qf[qg][dblk]; row=l15 (q within 16), k-offset g*8 within 32-d blk
  bf16x8 qf[2][2];
#pragma unroll
  for (int qg = 0; qg < 2; qg++)
#pragma unroll
    for (int db = 0; db < 2; db++)
      qf[qg][db] = *(const bf16x8*)(qbase + (size_t)(q0 + w * 32 + qg * 16 + l15) * 3072 + db * 32 + g * 8);

  float m_[2][4], l_[2][4];
  f32x4 accO[2][4];
#pragma unroll
  for (int qg = 0; qg < 2; qg++) {
#pragma unroll
    for (int r = 0; r < 4; r++) { m_[qg][r] = -1e30f; l_[qg][r] = 0.f; }
#pragma unroll
    for (int dt = 0; dt < 4; dt++) { f32x4 z = {0,0,0,0}; accO[qg][dt] = z; }
  }

  const int tstart = (q0 == 0) ? 1 : 0;
  for (int tile = tstart; tile < 2; tile++) {
    const int base = q0 - 128 + tile * 128;  // >= 0 whenever executed
    __syncthreads();
    // stage K rows [base, base+128): coalesced reads, padded rows
#pragma unroll
    for (int i = 0; i < 4; i++) {
      const int c = i * 256 + t;       // 1024 chunks of 8 bf16
      const int k = c >> 3, dc = c & 7;
      *(bf16x8*)&Kl[k * 72 + dc * 8] = *(const bf16x8*)(kbase + (size_t)(base + k) * 3072 + dc * 8);
    }
    // stage V transposed: thread t -> row k=t&127, d-half (t>>7)*32; scatter writes 2-way conflict
    {
      const int k = t & 127, dh = (t >> 7) * 32;
#pragma unroll
      for (int i = 0; i < 4; i++) {
        bf16x8 v = *(const bf16x8*)(vbase + (size_t)(base + k) * 3072 + dh + i * 8);
#pragma unroll
        for (int j = 0; j < 8; j++)
          Vt[(dh + i * 8 + j) * 136 + k] = v[j];
      }
    }
    __syncthreads();

    // per-wave computed 16-key tile range (skip fully-masked)
    const int kt_lo = (tile == 0) ? 2 * w : 0;
    const int kt_hi = (tile == 0) ? 8 : 2 * w + 2;
    const int nkt = kt_hi - kt_lo;

    f32x4 s[2][8];
#pragma unroll
    for (int qg = 0; qg < 2; qg++)
#pragma unroll
      for (int kk = 0; kk < 8; kk++) { f32x4 z = {0,0,0,0}; s[qg][kk] = z; }

    // QK^T
#pragma unroll
    for (int kk = 0; kk < 8; kk++) {
      if (kk >= nkt) continue;
      const int kt = kt_lo + kk;
      const bf16x8 kf0 = *(const bf16x8*)&Kl[(kt * 16 + l15) * 72 + g * 8];
      const bf16x8 kf1 = *(const bf16x8*)&Kl[(kt * 16 + l15) * 72 + 32 + g * 8];
      s[0][kk] = __builtin_amdgcn_mfma_f32_16x16x32_bf16(qf[0][0], kf0, s[0][kk], 0, 0, 0);
      s[0][kk] = __builtin_amdgcn_mfma_f32_16x16x32_bf16(qf[0][1], kf1, s[0][kk], 0, 0, 0);
      s[1][kk] = __builtin_amdgcn_mfma_f32_16x16x32_bf16(qf[1][0], kf0, s[1][kk], 0, 0, 0);
      s[1][kk] = __builtin_amdgcn_mfma_f32_16x16x32_bf16(qf[1][1], kf1, s[1][kk], 0, 0, 0);
    }

#pragma unroll
    for (int qg = 0; qg < 2; qg++) {
      // mask + scale
#pragma unroll
      for (int kk = 0; kk < 8; kk++) {
        if (kk >= nkt) continue;
        const int kr = (kt_lo + kk) * 16 + l15;
#pragma unroll
        for (int r = 0; r < 4; r++) {
          const int qr = w * 32 + qg * 16 + g * 4 + r;
          const bool ok = (tile == 0) ? (kr >= qr) : (kr < qr);
          s[qg][kk][r] = ok ? s[qg][kk][r] * 0.125f : -1e9f;
        }
      }
      // row max (16-lane groups hold one row per reg)
      float corr[4];
#pragma unroll
      for (int r = 0; r < 4; r++) {
        float v = -1e30f;
#pragma unroll
        for (int kk = 0; kk < 8; kk++) { if (kk >= nkt) continue; v = fmaxf(v, s[qg][kk][r]); }
        v = fmaxf(v, __shfl_xor(v, 1));
        v = fmaxf(v, __shfl_xor(v, 2));
        v = fmaxf(v, __shfl_xor(v, 4));
        v = fmaxf(v, __shfl_xor(v, 8));
        const float mn = fmaxf(m_[qg][r], v);
        corr[r] = __expf(m_[qg][r] - mn);
        m_[qg][r] = mn;
      }
      // p = exp(s-m), row sums, write P (bf16) to per-wave LDS
      float rs[4] = {0.f, 0.f, 0.f, 0.f};
#pragma unroll
      for (int kk = 0; kk < 8; kk++) {
        if (kk >= nkt) continue;
        const int kt = kt_lo + kk;
#pragma unroll
        for (int r = 0; r < 4; r++) {
          const float sv = s[qg][kk][r];
          const float p = (sv > -5e8f) ? __expf(sv - m_[qg][r]) : 0.f;
          rs[r] += p;
          Pl[w][(g * 4 + r) * 136 + kt * 16 + l15] = (bf16)p;
        }
      }
#pragma unroll
      for (int r = 0; r < 4; r++) {
        float v = rs[r];
        v += __shfl_xor(v, 1); v += __shfl_xor(v, 2);
        v += __shfl_xor(v, 4); v += __shfl_xor(v, 8);
        l_[qg][r] = l_[qg][r] * corr[r] + v;
#pragma unroll
        for (int dt = 0; dt < 4; dt++) accO[qg][dt][r] *= corr[r];
      }
      asm volatile("s_waitcnt lgkmcnt(0)" ::: "memory");
      __builtin_amdgcn_sched_barrier(0);
      // PV for this qg (skip fully-masked 32-key chunks)
      const int kc_lo = (tile == 0) ? w : 0;
      const int kc_hi = (tile == 0) ? 4 : w + 1;
#pragma unroll
      for (int kc = 0; kc < 4; kc++) {
        if (kc < kc_lo || kc >= kc_hi) continue;
        const bf16x8 pa = *(const bf16x8*)&Pl[w][l15 * 136 + kc * 32 + g * 8];
#pragma unroll
        for (int dt = 0; dt < 4; dt++) {
          const bf16x8 vf = *(const bf16x8*)&Vt[(dt * 16 + l15) * 136 + kc * 32 + g * 8];
          accO[qg][dt] = __builtin_amdgcn_mfma_f32_16x16x32_bf16(pa, vf, accO[qg][dt], 0, 0, 0);
        }
      }
    }
  }

  bf16* outp = localb + ((size_t)b * S_ + q0 + w * 32) * 1024 + h * 64;
#pragma unroll
  for (int qg = 0; qg < 2; qg++)
#pragma unroll
    for (int r = 0; r < 4; r++) {
      const float inv = (l_[qg][r] > 0.f) ? 1.f / l_[qg][r] : 0.f;
#pragma unroll
      for (int dt = 0; dt < 4; dt++)
        outp[(size_t)(qg * 16 + g * 4 + r) * 1024 + dt * 16 + l15] = (bf16)(accO[qg][dt][r] * inv);
    }
}

// ---------------- gate + mix ----------------
__global__ __launch_bounds__(1024) void gate_mix_kernel(
    const bf16* __restrict__ localb, const bf16* __restrict__ remote,
    const float* __restrict__ glw, const float* __restrict__ grw,
    bf16* __restrict__ mixed)
{
  const int blk = blockIdx.x;
  const int b = blk >> 12, s = blk & 4095;
  const int t = threadIdx.x;
  const int d = t & 63;
  const size_t idx = ((size_t)b * S_ + s) * 1024 + t;
  const float lf = (float)localb[idx], rf = (float)remote[idx];
  float part = lf * glw[d] + rf * grw[d];
#pragma unroll
  for (int off = 32; off; off >>= 1) part += __shfl_xor(part, off);
  const float g = 1.f / (1.f + __expf(-part));
  mixed[idx] = (bf16)(g * lf + (1.f - g) * rf);
}

// ---------------- launch ----------------
extern "C" void kernel_launch(void* const* d_in, const int* in_sizes, int n_in,
                              void* d_out, int out_size, void* d_ws, size_t ws_size,
                              hipStream_t stream)
{
  const float* x      = (const float*)d_in[0];
  const float* qkv_w  = (const float*)d_in[1];
  const float* qkv_b  = (const float*)d_in[2];
  const float* rq_w   = (const float*)d_in[3];
  const float* rq_b   = (const float*)d_in[4];
  const float* rkv_w  = (const float*)d_in[5];
  const float* rkv_b  = (const float*)d_in[6];
  const float* rout_w = (const float*)d_in[7];
  const float* rout_b = (const float*)d_in[8];
  const float* out_w  = (const float*)d_in[9];
  const float* out_b  = (const float*)d_in[10];
  const float* gl_w   = (const float*)d_in[11];
  const float* gr_w   = (const float*)d_in[12];

  char* w = (char*)d_ws;
  bf16* qkv_wt = (bf16*)w; w += (size_t)3072 * 1024 * 2;
  bf16* rq_wt  = (bf16*)w; w += (size_t)256 * 1024 * 2;
  bf16* rkv_wt = (bf16*)w; w += (size_t)512 * 1024 * 2;
  bf16* rout_wt= (bf16*)w; w += (size_t)1024 * 256 * 2;
  bf16* out_wt = (bf16*)w; w += (size_t)1024 * 1024 * 2;
  bf16* xb     = (bf16*)w; w += (size_t)B_ * S_ * 1024 * 2;
  bf16* qkvb   = (bf16*)w; w += (size_t)B_ * S_ * 3072 * 2;
  bf16* pooled = (bf16*)w; w += (size_t)B_ * 64 * 1024 * 2;
  bf16* rqb    = (bf16*)w; w += (size_t)B_ * S_ * 256 * 2;
  bf16* rkvb   = (bf16*)w; w += (size_t)B_ * 64 * 512 * 2;
  bf16* latout = (bf16*)w; w += (size_t)B_ * S_ * 256 * 2;
  bf16* remote = (bf16*)w; w += (size_t)B_ * S_ * 1024 * 2;
  bf16* localb = (bf16*)w; w += (size_t)B_ * S_ * 1024 * 2;
  bf16* mixed  = qkvb;  // reuse: qkvb dead after local_attn

  const dim3 tb(32, 8);
  transpose_convert<<<dim3(96, 32), tb, 0, stream>>>(qkv_w, qkv_wt, 1024, 3072);
  transpose_convert<<<dim3(8, 32),  tb, 0, stream>>>(rq_w, rq_wt, 1024, 256);
  transpose_convert<<<dim3(16, 32), tb, 0, stream>>>(rkv_w, rkv_wt, 1024, 512);
  transpose_convert<<<dim3(32, 8),  tb, 0, stream>>>(rout_w, rout_wt, 256, 1024);
  transpose_convert<<<dim3(32, 32), tb, 0, stream>>>(out_w, out_wt, 1024, 1024);
  convert_kernel<<<dim3(2048), 256, 0, stream>>>(x, xb, B_ * S_ * 1024 / 4);

  gemm_bias_kernel<bf16><<<dim3(64, 24), 256, 0, stream>>>(xb, qkv_wt, qkv_b, qkvb, B_ * S_, 3072, 1024);
  pool_kernel<<<dim3(B_ * 64), 256, 0, stream>>>(x, pooled);
  gemm_bias_kernel<bf16><<<dim3(64, 2), 256, 0, stream>>>(xb, rq_wt, rq_b, rqb, B_ * S_, 256, 1024);
  gemm_bias_kernel<bf16><<<dim3(1, 4), 256, 0, stream>>>(pooled, rkv_wt, rkv_b, rkvb, B_ * 64, 512, 1024);
  latent_attn_kernel<<<dim3(B_ * S_), 256, 0, stream>>>(rqb, rkvb, latout);
  gemm_bias_kernel<bf16><<<dim3(64, 8), 256, 0, stream>>>(latout, rout_wt, rout_b, remote, B_ * S_, 1024, 256);
  local_attn_mfma<<<dim3(S_ / 128, 16, B_), 256, 0, stream>>>(qkvb, localb);
  gate_mix_kernel<<<dim3(B_ * S_), 1024, 0, stream>>>(localb, remote, gl_w, gr_w, mixed);
  gemm_bias_kernel<float><<<dim3(64, 8), 256, 0, stream>>>(mixed, out_wt, out_b, (float*)d_out, B_ * S_, 1024, 1024);
}